// Round 3
// baseline (285.055 us; speedup 1.0000x reference)
//
#include <hip/hip_runtime.h>
#include <hip/hip_bf16.h>

// Problem constants (reference: B,K,N,F,H = 20000,10,100000,256,128)
constexpr int B_ = 20000;
constexpr int K_ = 10;
constexpr int N_ = 100000;
constexpr int F_ = 256;
constexpr int H_ = 128;

typedef __attribute__((ext_vector_type(8))) short bf16x8;
typedef __attribute__((ext_vector_type(4))) float f32x4;
typedef __attribute__((ext_vector_type(4))) unsigned short ushort4v;

__device__ __forceinline__ unsigned short f2bf(float x) {
  // round-to-nearest-even fp32 -> bf16
  unsigned int u = __builtin_bit_cast(unsigned int, x);
  unsigned int r = u + 0x7fffu + ((u >> 16) & 1u);
  return (unsigned short)(r >> 16);
}

__device__ __forceinline__ float bf2f(unsigned int u16) {
  return __builtin_bit_cast(float, u16 << 16);
}

__device__ __forceinline__ float fast_tanh(float x) {
  float e = __expf(2.0f * x);
  return 1.0f - 2.0f * __builtin_amdgcn_rcpf(e + 1.0f);
}

// ---------------------------------------------------------------------------
// Prep: bf16-transpose the six weight matrices.
// wat[p][h][k] = Wa_p[k][h]  (3 x 128 x 256)
// wbt[p][h][k] = Wb_p[k][h]  (3 x 128 x 128)
// ---------------------------------------------------------------------------
__global__ __launch_bounds__(256) void prep_kernel(
    const float* __restrict__ W1a, const float* __restrict__ W1b,
    const float* __restrict__ W2a, const float* __restrict__ W2b,
    const float* __restrict__ W3a, const float* __restrict__ W3b,
    unsigned short* __restrict__ wat, unsigned short* __restrict__ wbt) {
  const float* Wa[3] = {W1a, W2a, W3a};
  const float* Wb[3] = {W1b, W2b, W3b};
  int g = blockIdx.x * 256 + threadIdx.x;
  if (g < 3 * F_ * H_) {
    int p = g >> 15;
    int r = g & (F_ * H_ - 1);
    int h = r >> 8;
    int k = r & 255;
    wat[g] = f2bf(Wa[p][k * H_ + h]);
  } else {
    int g2 = g - 3 * F_ * H_;
    int p = g2 >> 14;
    int r = g2 & (H_ * H_ - 1);
    int h = r >> 7;
    int k = r & 127;
    wbt[g2] = f2bf(Wb[p][k * H_ + h]);
  }
}

// ---------------------------------------------------------------------------
// Phase 1 (MFMA): per-node q/k/v projections.
// Block = 256 threads (4 waves), MT=32 nodes (N_ % 32 == 0 -> no bounds checks).
// Wave w owns output cols [32w,32w+32). B-fragments preloaded into register
// arrays (16 global loads in flight at once) to break the load->MFMA
// dependency stall seen in round 2 (VGPR=68, MfmaUtil 9%).
// LDS 25.6 KB -> 4 blocks/CU with __launch_bounds__(256,4).
// ---------------------------------------------------------------------------
constexpr int MT = 32;
constexpr int XS = F_ + 8;  // 264 ushorts: 528 B row stride, 16B-aligned
constexpr int TS = H_ + 8;  // 136 ushorts: 272 B row stride

__global__ __launch_bounds__(256, 4) void proj_kernel(
    const float* __restrict__ E,
    const unsigned short* __restrict__ wat,
    const unsigned short* __restrict__ wbt,
    unsigned short* __restrict__ qo, unsigned short* __restrict__ ko,
    unsigned short* __restrict__ vo) {
  __shared__ unsigned short xs[MT * XS];  // 16.9 KB
  __shared__ unsigned short ts[MT * TS];  // 8.7 KB

  const int tid = threadIdx.x;
  const int lane = tid & 63;
  const int w = tid >> 6;
  const int l15 = lane & 15;
  const int kg = lane >> 4;
  const int row0 = blockIdx.x * MT;

  // ---- stage X tile (fp32 global -> bf16 LDS), coalesced dwordx4
  {
    const float4* Eg = (const float4*)E;
#pragma unroll
    for (int it = 0; it < 8; ++it) {
      int i = tid + 256 * it;
      int r = i >> 6;
      int c4 = i & 63;
      float4 v = Eg[(size_t)(row0 + r) * (F_ / 4) + c4];
      ushort4v o;
      o.x = f2bf(v.x); o.y = f2bf(v.y); o.z = f2bf(v.z); o.w = f2bf(v.w);
      *(ushort4v*)&xs[r * XS + c4 * 4] = o;
    }
  }
  __syncthreads();

  unsigned short* const outp[3] = {qo, ko, vo};

  for (int p = 0; p < 3; ++p) {
    const unsigned short* __restrict__ wap = wat + p * (F_ * H_);
    const unsigned short* __restrict__ wbp = wbt + p * (H_ * H_);

    // ---- preload ALL layer-1 B-fragments (16 loads in flight)
    bf16x8 b1r[8][2];
#pragma unroll
    for (int k = 0; k < 8; ++k) {
      const int koff = k * 32 + kg * 8;
      b1r[k][0] = *(const bf16x8*)&wap[(w * 32 + l15) * F_ + koff];
      b1r[k][1] = *(const bf16x8*)&wap[(w * 32 + 16 + l15) * F_ + koff];
    }

    // ---- layer 1: U = X @ Wa   (K=256, 8 k-steps)
    f32x4 acc[2][2];
#pragma unroll
    for (int rt = 0; rt < 2; ++rt)
#pragma unroll
      for (int c = 0; c < 2; ++c) acc[rt][c] = (f32x4)0.0f;

#pragma unroll
    for (int k = 0; k < 8; ++k) {
      const int koff = k * 32 + kg * 8;
      bf16x8 a0 = *(const bf16x8*)&xs[l15 * XS + koff];
      bf16x8 a1 = *(const bf16x8*)&xs[(16 + l15) * XS + koff];
      acc[0][0] = __builtin_amdgcn_mfma_f32_16x16x32_bf16(a0, b1r[k][0], acc[0][0], 0, 0, 0);
      acc[0][1] = __builtin_amdgcn_mfma_f32_16x16x32_bf16(a0, b1r[k][1], acc[0][1], 0, 0, 0);
      acc[1][0] = __builtin_amdgcn_mfma_f32_16x16x32_bf16(a1, b1r[k][0], acc[1][0], 0, 0, 0);
      acc[1][1] = __builtin_amdgcn_mfma_f32_16x16x32_bf16(a1, b1r[k][1], acc[1][1], 0, 0, 0);
    }

    // ---- preload layer-2 B-fragments (overlaps the barrier below)
    bf16x8 b2r[4][2];
#pragma unroll
    for (int k = 0; k < 4; ++k) {
      const int koff = k * 32 + kg * 8;
      b2r[k][0] = *(const bf16x8*)&wbp[(w * 32 + l15) * H_ + koff];
      b2r[k][1] = *(const bf16x8*)&wbp[(w * 32 + 16 + l15) * H_ + koff];
    }

    // ---- tanh in regs, then LDS round-trip (C/D layout -> A layout)
    unsigned short tv[2][2][4];
#pragma unroll
    for (int rt = 0; rt < 2; ++rt)
#pragma unroll
      for (int c = 0; c < 2; ++c)
#pragma unroll
        for (int r = 0; r < 4; ++r)
          tv[rt][c][r] = f2bf(fast_tanh(acc[rt][c][r]));

    __syncthreads();  // prior projection's ts reads complete
#pragma unroll
    for (int rt = 0; rt < 2; ++rt)
#pragma unroll
      for (int c = 0; c < 2; ++c)
#pragma unroll
        for (int r = 0; r < 4; ++r)
          ts[(rt * 16 + kg * 4 + r) * TS + w * 32 + c * 16 + l15] = tv[rt][c][r];
    __syncthreads();

    // ---- layer 2: P = T @ Wb   (K=128, 4 k-steps)
    f32x4 ac2[2][2];
#pragma unroll
    for (int rt = 0; rt < 2; ++rt)
#pragma unroll
      for (int c = 0; c < 2; ++c) ac2[rt][c] = (f32x4)0.0f;

#pragma unroll
    for (int k = 0; k < 4; ++k) {
      const int koff = k * 32 + kg * 8;
      bf16x8 a0 = *(const bf16x8*)&ts[l15 * TS + koff];
      bf16x8 a1 = *(const bf16x8*)&ts[(16 + l15) * TS + koff];
      ac2[0][0] = __builtin_amdgcn_mfma_f32_16x16x32_bf16(a0, b2r[k][0], ac2[0][0], 0, 0, 0);
      ac2[0][1] = __builtin_amdgcn_mfma_f32_16x16x32_bf16(a0, b2r[k][1], ac2[0][1], 0, 0, 0);
      ac2[1][0] = __builtin_amdgcn_mfma_f32_16x16x32_bf16(a1, b2r[k][0], ac2[1][0], 0, 0, 0);
      ac2[1][1] = __builtin_amdgcn_mfma_f32_16x16x32_bf16(a1, b2r[k][1], ac2[1][1], 0, 0, 0);
    }

    // ---- store P as bf16
    unsigned short* __restrict__ o = outp[p];
#pragma unroll
    for (int rt = 0; rt < 2; ++rt)
#pragma unroll
      for (int c = 0; c < 2; ++c)
#pragma unroll
        for (int r = 0; r < 4; ++r) {
          int n = row0 + rt * 16 + kg * 4 + r;
          o[(size_t)n * H_ + w * 32 + c * 16 + l15] = f2bf(ac2[rt][c][r]);
        }
  }
}

// ---------------------------------------------------------------------------
// Phase 2: one WAVE per batch node. No LDS, no barriers.
// scores = Q K^T via MFMA on gathered frags (A/B lane patterns identical:
// lane reads 16B of row nb[lane&15]); softmax via width-16 shuffles;
// colsum via quad shuffles; out = colsum . V with broadcast scalars.
// ---------------------------------------------------------------------------
__global__ __launch_bounds__(256) void agg_kernel(
    const int* __restrict__ nbr,
    const unsigned short* __restrict__ qa,
    const unsigned short* __restrict__ ka,
    const unsigned short* __restrict__ va,
    float* __restrict__ out) {
  const int lane = threadIdx.x & 63;
  const int wv = threadIdx.x >> 6;
  const int b = blockIdx.x * 4 + wv;
  const int l15 = lane & 15;
  const int kg = lane >> 4;

  // neighbor id for this lane's row slot (clamp rows 10..15; masked later)
  const int ni = nbr[b * K_ + (l15 < K_ ? l15 : 0)];

  // scores[i][j] = q_i . k_j : A = Q rows (m=i), B = K rows (n=j)
  f32x4 sc = (f32x4)0.0f;
#pragma unroll
  for (int k = 0; k < 4; ++k) {
    const int off = k * 32 + kg * 8;
    bf16x8 qf = *(const bf16x8*)&qa[(size_t)ni * H_ + off];
    bf16x8 kf = *(const bf16x8*)&ka[(size_t)ni * H_ + off];
    sc = __builtin_amdgcn_mfma_f32_16x16x32_bf16(qf, kf, sc, 0, 0, 0);
  }
  // C layout: row i = kg*4 + r, col j = l15

  // mask invalid cols (j >= 10) so exp -> 0
  if (l15 >= K_) {
#pragma unroll
    for (int r = 0; r < 4; ++r) sc[r] = -3.0e38f;
  }

  // row-wise softmax over the 16 cols (lanes within a quad)
  float mx[4], e[4], sm[4];
#pragma unroll
  for (int r = 0; r < 4; ++r) mx[r] = sc[r];
#pragma unroll
  for (int st = 1; st < 16; st <<= 1)
#pragma unroll
    for (int r = 0; r < 4; ++r) mx[r] = fmaxf(mx[r], __shfl_xor(mx[r], st, 16));
#pragma unroll
  for (int r = 0; r < 4; ++r) { e[r] = __expf(sc[r] - mx[r]); sm[r] = e[r]; }
#pragma unroll
  for (int st = 1; st < 16; st <<= 1)
#pragma unroll
    for (int r = 0; r < 4; ++r) sm[r] += __shfl_xor(sm[r], st, 16);

  // att + zero invalid rows (i >= 10), then column sums over i
  float cs = 0.0f;
#pragma unroll
  for (int r = 0; r < 4; ++r) {
    float a = e[r] * __builtin_amdgcn_rcpf(sm[r]);
    if (kg * 4 + r >= K_) a = 0.0f;
    cs += a;
  }
  cs += __shfl_xor(cs, 16, 64);
  cs += __shfl_xor(cs, 32, 64);
  // now lane holds colsum[j = l15] (lanes j>=10 hold 0)

  // out[b,d] = sum_j colsum[j] * V[j][d]; lane handles d = 2*lane, 2*lane+1
  float o0 = 0.0f, o1 = 0.0f;
#pragma unroll
  for (int j = 0; j < K_; ++j) {
    const float cj = __shfl(cs, j, 64);
    const int nj = __shfl(ni, j, 64);
    const unsigned int v2 = *(const unsigned int*)&va[(size_t)nj * H_ + 2 * lane];
    o0 = fmaf(cj, bf2f(v2 & 0xffffu), o0);
    o1 = fmaf(cj, bf2f(v2 >> 16), o1);
  }
  *(float2*)&out[(size_t)b * H_ + 2 * lane] = make_float2(o0, o1);
}

extern "C" void kernel_launch(void* const* d_in, const int* in_sizes, int n_in,
                              void* d_out, int out_size, void* d_ws, size_t ws_size,
                              hipStream_t stream) {
  const int* nbr = (const int*)d_in[0];
  const float* E = (const float*)d_in[1];
  const float* W1a = (const float*)d_in[2];
  const float* W1b = (const float*)d_in[3];
  const float* W2a = (const float*)d_in[4];
  const float* W2b = (const float*)d_in[5];
  const float* W3a = (const float*)d_in[6];
  const float* W3b = (const float*)d_in[7];
  float* out = (float*)d_out;

  // workspace: qa/ka/va 3x[N,H] bf16 = 76.8 MB, then transposed bf16 weights
  unsigned short* qa = (unsigned short*)d_ws;
  unsigned short* ka = qa + (size_t)N_ * H_;
  unsigned short* va = ka + (size_t)N_ * H_;
  unsigned short* wat = va + (size_t)N_ * H_;
  unsigned short* wbt = wat + (size_t)3 * F_ * H_;

  prep_kernel<<<(3 * F_ * H_ + 3 * H_ * H_) / 256, 256, 0, stream>>>(
      W1a, W1b, W2a, W2b, W3a, W3b, wat, wbt);
  proj_kernel<<<N_ / MT, 256, 0, stream>>>(E, wat, wbt, qa, ka, va);
  agg_kernel<<<B_ / 4, 256, 0, stream>>>(nbr, qa, ka, va, out);
}